// Round 1
// baseline (746.465 us; speedup 1.0000x reference)
//
#include <hip/hip_runtime.h>
#include <stdint.h>

// Problem constants (B=1)
#define H_  12
#define DH_ 64
#define D_  768
#define TD_ 2304      // 3*D
#define E_  128
#define L_  256
#define M_  (E_*L_)   // 32768 rows
#define KDIM_ 768

typedef __bf16 bf16x8 __attribute__((ext_vector_type(8)));
typedef float  f32x4  __attribute__((ext_vector_type(4)));

__device__ __forceinline__ float b2f(unsigned short u) {
    return __uint_as_float(((unsigned int)u) << 16);
}
__device__ __forceinline__ unsigned short f2b(float f) {
    unsigned int u = __float_as_uint(f);
    u += 0x7fffu + ((u >> 16) & 1u);   // RNE
    return (unsigned short)(u >> 16);
}

union frag_u { unsigned short u[8]; bf16x8 v; };

#define GLOBAL_AS(p) ((const __attribute__((address_space(1))) void*)(p))
#define LDS_AS(p)    ((__attribute__((address_space(3))) void*)(p))

// ---------------------------------------------------------------------------
// fp32 -> bf16, 4 elements/thread (n % 4 == 0)
// ---------------------------------------------------------------------------
__global__ __launch_bounds__(256) void cvt4(
    const float4* __restrict__ src, ushort4* __restrict__ dst, int n4)
{
    int i = blockIdx.x * 256 + threadIdx.x;
    if (i < n4) {
        float4 f = src[i];
        ushort4 o;
        o.x = f2b(f.x); o.y = f2b(f.y); o.z = f2b(f.z); o.w = f2b(f.w);
        dst[i] = o;
    }
}

// ---------------------------------------------------------------------------
// C[M,2304](bf16) = A[M,768](bf16) @ Wb[2304,768](bf16)^T + bias(fp32)
// m97 structure: 128x128 tile, BK=32, global_load_lds width 16, 4 waves,
// 4x4 16x16x32 MFMA per wave. LDS chunk swizzle: element (R, colgroup c)
// stored at chunk R*4 + ((c + (R>>1)) & 3)  -> frag reads are 2-way (free).
// T1: XCD-aware bijective chunked blockIdx swizzle (nwg=4608, %8==0) so
// each XCD gets 32 contiguous m-strips x all 18 n-blocks -> A-panel and Wb
// stay resident in that XCD's L2 instead of being re-fetched by 8 XCDs.
// ---------------------------------------------------------------------------
__global__ __launch_bounds__(256) void gemm_lds(
    const unsigned short* __restrict__ A,
    const unsigned short* __restrict__ Wb,
    const float* __restrict__ bias,
    unsigned short* __restrict__ C)
{
    __shared__ unsigned short As[128 * 32];   // 8 KB
    __shared__ unsigned short Bs[128 * 32];   // 8 KB

    const int tid  = threadIdx.x;
    const int lane = tid & 63;
    const int w    = tid >> 6;
    const int l15  = lane & 15;
    const int quad = lane >> 4;

    // T1 XCD swizzle: linear id with x fastest; 4608 blocks = 8 XCDs * 576.
    const int bid = blockIdx.y * gridDim.x + blockIdx.x;
    const int cpx = (gridDim.x * gridDim.y) >> 3;       // 576
    const int swz = (bid & 7) * cpx + (bid >> 3);
    const int n_blk = (swz % gridDim.x) * 128;
    const int m_blk = (swz / gridDim.x) * 128;

    const int wm = (w >> 1) * 64;
    const int wn = (w & 1) * 64;

    // staging: lane's LDS slot is fixed (chunk = s*256 + w*64 + lane); choose
    // the global colgroup that belongs in that slot: cc = ((lane&3)-(R>>1))&3,
    // which reduces to ((lane&3) - (lane>>3)) & 3 (wave/issue terms are %4==0).
    const int cc   = ((lane & 3) - (lane >> 3)) & 3;
    const int rloc = lane >> 2;
    const unsigned short* gA0 = A  + (size_t)(m_blk + w * 16 + rloc) * KDIM_ + cc * 8;
    const unsigned short* gA1 = gA0 + (size_t)64 * KDIM_;
    const unsigned short* gB0 = Wb + (size_t)(n_blk + w * 16 + rloc) * KDIM_ + cc * 8;
    const unsigned short* gB1 = gB0 + (size_t)64 * KDIM_;

    char* asb = (char*)As;
    char* bsb = (char*)Bs;
    char* dA0 = asb + w * 1024;
    char* dA1 = asb + 4096 + w * 1024;
    char* dB0 = bsb + w * 1024;
    char* dB1 = bsb + 4096 + w * 1024;

    // fragment read byte-offsets (constant over K loop)
    int offA[4], offB[4];
    #pragma unroll
    for (int t = 0; t < 4; t++) {
        int Ra = wm + t * 16 + l15;
        offA[t] = (Ra * 4 + ((quad + (Ra >> 1)) & 3)) * 16;
        int Rb = wn + t * 16 + l15;
        offB[t] = (Rb * 4 + ((quad + (Rb >> 1)) & 3)) * 16;
    }

    f32x4 acc[4][4];
    #pragma unroll
    for (int i = 0; i < 4; i++)
        #pragma unroll
        for (int j = 0; j < 4; j++) acc[i][j] = (f32x4){0.f, 0.f, 0.f, 0.f};

    for (int kb = 0; kb < KDIM_ / 32; kb++) {
        __builtin_amdgcn_global_load_lds(GLOBAL_AS(gA0), LDS_AS(dA0), 16, 0, 0);
        __builtin_amdgcn_global_load_lds(GLOBAL_AS(gA1), LDS_AS(dA1), 16, 0, 0);
        __builtin_amdgcn_global_load_lds(GLOBAL_AS(gB0), LDS_AS(dB0), 16, 0, 0);
        __builtin_amdgcn_global_load_lds(GLOBAL_AS(gB1), LDS_AS(dB1), 16, 0, 0);
        gA0 += 32; gA1 += 32; gB0 += 32; gB1 += 32;
        __syncthreads();   // drains vmcnt -> staged tiles visible

        bf16x8 af[4], bfr[4];
        #pragma unroll
        for (int t = 0; t < 4; t++) af[t]  = *(const bf16x8*)(const void*)(asb + offA[t]);
        #pragma unroll
        for (int t = 0; t < 4; t++) bfr[t] = *(const bf16x8*)(const void*)(bsb + offB[t]);
        #pragma unroll
        for (int mt = 0; mt < 4; mt++)
            #pragma unroll
            for (int nt = 0; nt < 4; nt++)
                acc[mt][nt] = __builtin_amdgcn_mfma_f32_16x16x32_bf16(
                    af[mt], bfr[nt], acc[mt][nt], 0, 0, 0);
        __syncthreads();   // before next staging overwrites tiles
    }

    // epilogue: C[row=quad*4+r][col=l15] per tile (verified layout)
    #pragma unroll
    for (int nt = 0; nt < 4; nt++) {
        int col = n_blk + wn + nt * 16 + l15;
        float bi = bias[col];
        #pragma unroll
        for (int mt = 0; mt < 4; mt++) {
            int rbase = m_blk + wm + mt * 16 + quad * 4;
            #pragma unroll
            for (int r = 0; r < 4; r++)
                C[(size_t)(rbase + r) * TD_ + col] = f2b(acc[mt][nt][r] + bi);
        }
    }
}

// ---------------------------------------------------------------------------
// MFMA attention. One (outer,h) per block, 4 waves, 256 threads.
// MODE 0: row attn (n=256 over L);  MODE 1: col attn (n=128 over E)
// ---------------------------------------------------------------------------
template<int MODE>
__global__ __launch_bounds__(256) void attn_mfma(
    const unsigned short* __restrict__ qkv,
    unsigned short* __restrict__ attnout,
    const int* __restrict__ mask)
{
    constexpr int N  = (MODE == 0) ? L_ : E_;
    constexpr int NT = N / 16;
    constexpr int KS = N / 32;
    constexpr int HALVES = N / 128;
    constexpr int MT = N / 64;

    __shared__ unsigned short VtS[64 * N];
    __shared__ unsigned short Ps[4][16][136];

    const int tid  = threadIdx.x;
    const int lane = tid & 63;
    const int w    = tid >> 6;
    const int quad = lane >> 4;
    const int l15  = lane & 15;
    const int hh    = blockIdx.x % H_;
    const int outer = blockIdx.x / H_;

    size_t base, stride, obase, ostride; int mbase, mstride;
    if (MODE == 0) {
        stride = TD_;              base = (size_t)outer * L_ * TD_;
        obase  = (size_t)outer * L_ * D_;  ostride = D_;
        mbase  = outer * L_;       mstride = 1;
    } else {
        stride = (size_t)L_ * TD_; base = (size_t)outer * TD_;
        obase  = (size_t)outer * D_;       ostride = (size_t)L_ * D_;
        mbase  = outer;            mstride = L_;
    }
    const unsigned short* Qg = qkv + base + hh * DH_;
    const unsigned short* Kg = Qg + D_;
    const unsigned short* Vg = Qg + 2 * D_;

    for (int c = tid; c < 4 * KS * 64; c += 256) {
        int tile = c >> 6, lc = c & 63;
        int qd = lc >> 4, fl = lc & 15;
        int dt = tile / KS, kt = tile % KS;
        int jb = kt * 32 + qd * 8;
        int d  = dt * 16 + fl;
        frag_u tmp;
        #pragma unroll
        for (int jj = 0; jj < 8; jj++)
            tmp.u[jj] = Vg[(size_t)(jb + jj) * stride + d];
        *(bf16x8*)(void*)&VtS[c * 8] = tmp.v;
    }

    float negreg[NT];
    #pragma unroll
    for (int nt = 0; nt < NT; nt++)
        negreg[nt] = mask[mbase + (nt * 16 + l15) * mstride] ? -10000.0f : 0.0f;

    __syncthreads();

    for (int mt = 0; mt < MT; mt++) {
        int m0 = (w * MT + mt) * 16;

        bf16x8 aq0 = *(const bf16x8*)(const void*)&Qg[(size_t)(m0 + l15) * stride + quad * 8];
        bf16x8 aq1 = *(const bf16x8*)(const void*)&Qg[(size_t)(m0 + l15) * stride + 32 + quad * 8];

        f32x4 sc[NT];
        #pragma unroll
        for (int nt = 0; nt < NT; nt++) sc[nt] = (f32x4){0.f,0.f,0.f,0.f};
        #pragma unroll
        for (int nt = 0; nt < NT; nt++) {
            bf16x8 bk0 = *(const bf16x8*)(const void*)&Kg[(size_t)(nt*16 + l15) * stride + quad * 8];
            bf16x8 bk1 = *(const bf16x8*)(const void*)&Kg[(size_t)(nt*16 + l15) * stride + 32 + quad * 8];
            sc[nt] = __builtin_amdgcn_mfma_f32_16x16x32_bf16(aq0, bk0, sc[nt], 0, 0, 0);
            sc[nt] = __builtin_amdgcn_mfma_f32_16x16x32_bf16(aq1, bk1, sc[nt], 0, 0, 0);
        }

        float mx[4] = {-1e30f, -1e30f, -1e30f, -1e30f};
        #pragma unroll
        for (int nt = 0; nt < NT; nt++)
            #pragma unroll
            for (int r = 0; r < 4; r++) {
                float s = sc[nt][r] * 0.125f + negreg[nt];
                sc[nt][r] = s;
                mx[r] = fmaxf(mx[r], s);
            }
        #pragma unroll
        for (int r = 0; r < 4; r++) {
            mx[r] = fmaxf(mx[r], __shfl_xor(mx[r], 1));
            mx[r] = fmaxf(mx[r], __shfl_xor(mx[r], 2));
            mx[r] = fmaxf(mx[r], __shfl_xor(mx[r], 4));
            mx[r] = fmaxf(mx[r], __shfl_xor(mx[r], 8));
        }
        float sum[4] = {0.f, 0.f, 0.f, 0.f};
        #pragma unroll
        for (int nt = 0; nt < NT; nt++)
            #pragma unroll
            for (int r = 0; r < 4; r++) {
                float p = __expf(sc[nt][r] - mx[r]);
                sc[nt][r] = p;
                sum[r] += p;
            }
        #pragma unroll
        for (int r = 0; r < 4; r++) {
            sum[r] += __shfl_xor(sum[r], 1);
            sum[r] += __shfl_xor(sum[r], 2);
            sum[r] += __shfl_xor(sum[r], 4);
            sum[r] += __shfl_xor(sum[r], 8);
        }

        f32x4 oacc[4];
        #pragma unroll
        for (int dt = 0; dt < 4; dt++) oacc[dt] = (f32x4){0.f,0.f,0.f,0.f};

        #pragma unroll
        for (int h2 = 0; h2 < HALVES; h2++) {
            #pragma unroll
            for (int t = 0; t < 8; t++)
                #pragma unroll
                for (int r = 0; r < 4; r++)
                    Ps[w][quad * 4 + r][t * 16 + l15] = f2b(sc[h2 * 8 + t][r]);
            #pragma unroll
            for (int kt = 0; kt < 4; kt++) {
                bf16x8 ap = *(const bf16x8*)(const void*)&Ps[w][l15][kt * 32 + quad * 8];
                #pragma unroll
                for (int dt = 0; dt < 4; dt++) {
                    bf16x8 bv = *(const bf16x8*)(const void*)
                        &VtS[((dt * KS + h2 * 4 + kt) * 64 + lane) * 8];
                    oacc[dt] = __builtin_amdgcn_mfma_f32_16x16x32_bf16(ap, bv, oacc[dt], 0, 0, 0);
                }
            }
        }

        float inv[4];
        #pragma unroll
        for (int r = 0; r < 4; r++) inv[r] = 1.0f / sum[r];
        #pragma unroll
        for (int dt = 0; dt < 4; dt++)
            #pragma unroll
            for (int r = 0; r < 4; r++) {
                size_t oaddr = obase + (size_t)(m0 + quad * 4 + r) * ostride
                             + hh * DH_ + dt * 16 + l15;
                attnout[oaddr] = f2b(oacc[dt][r] * inv[r]);
            }
    }
}

// ---------------------------------------------------------------------------
// out = LayerNorm(x + r) * g + beta — one wave per row.
// XBF16: residual input dtype; OBF16: output dtype.
// ---------------------------------------------------------------------------
template<int XBF16, int OBF16>
__global__ __launch_bounds__(256) void add_ln(
    const void* __restrict__ xp,
    const unsigned short* __restrict__ r,
    const float* __restrict__ g,
    const float* __restrict__ bta,
    void* __restrict__ outp)
{
    int row  = blockIdx.x * 4 + (threadIdx.x >> 6);
    int lane = threadIdx.x & 63;
    size_t off = (size_t)row * D_;
    const float* xf = (const float*)xp;
    const unsigned short* xb = (const unsigned short*)xp;
    float v[12];
    float sum = 0.f;
    #pragma unroll
    for (int j = 0; j < 12; j++) {
        int c = j * 64 + lane;
        float xv = XBF16 ? b2f(xb[off + c]) : xf[off + c];
        v[j] = xv + b2f(r[off + c]);
        sum += v[j];
    }
    for (int o = 32; o; o >>= 1) sum += __shfl_xor(sum, o);
    float mu = sum * (1.0f / 768.0f);
    float s2 = 0.f;
    #pragma unroll
    for (int j = 0; j < 12; j++) { float d = v[j] - mu; s2 = fmaf(d, d, s2); }
    for (int o = 32; o; o >>= 1) s2 += __shfl_xor(s2, o);
    float rs = rsqrtf(s2 * (1.0f / 768.0f) + 1e-5f);
    #pragma unroll
    for (int j = 0; j < 12; j++) {
        int c = j * 64 + lane;
        float y = (v[j] - mu) * rs * g[c] + bta[c];
        if (OBF16) ((unsigned short*)outp)[off + c] = f2b(y);
        else       ((float*)outp)[off + c] = y;
    }
}

// ---------------------------------------------------------------------------
extern "C" void kernel_launch(void* const* d_in, const int* in_sizes, int n_in,
                              void* d_out, int out_size, void* d_ws, size_t ws_size,
                              hipStream_t stream)
{
    const float* x     = (const float*)d_in[0];
    const float* w_row = (const float*)d_in[1];
    const float* b_row = (const float*)d_in[2];
    const float* w_col = (const float*)d_in[3];
    const float* b_col = (const float*)d_in[4];
    const float* g1    = (const float*)d_in[5];
    const float* be1   = (const float*)d_in[6];
    const float* g2    = (const float*)d_in[7];
    const float* be2   = (const float*)d_in[8];
    const int*   mask  = (const int*)d_in[9];
    float* out = (float*)d_out;

    char* ws = (char*)d_ws;
    size_t o = 0;
    unsigned short* qkv   = (unsigned short*)(ws + o); o += (size_t)M_ * TD_ * 2;    // 151 MB
    unsigned short* attn  = (unsigned short*)(ws + o); o += (size_t)M_ * D_ * 2;     // 48 MB (aliases xb)
    unsigned short* out1b = (unsigned short*)(ws + o); o += (size_t)M_ * D_ * 2;     // 48 MB
    unsigned short* wbr   = (unsigned short*)(ws + o); o += (size_t)TD_ * KDIM_ * 2; // 3.4 MB
    unsigned short* wbc   = (unsigned short*)(ws + o);                               // 3.4 MB
    unsigned short* xb    = attn;   // safe alias: xb consumed by gemm1 before attn<0> writes

    int wn4 = TD_ * KDIM_ / 4;
    int xn4 = M_ * D_ / 4;
    cvt4<<<(wn4 + 255) / 256, 256, 0, stream>>>((const float4*)w_row, (ushort4*)wbr, wn4);
    cvt4<<<(wn4 + 255) / 256, 256, 0, stream>>>((const float4*)w_col, (ushort4*)wbc, wn4);
    cvt4<<<(xn4 + 255) / 256, 256, 0, stream>>>((const float4*)x, (ushort4*)xb, xn4);

    dim3 gg(TD_ / 128, M_ / 128);   // 18 x 256 blocks

    // ---- row attention ----
    gemm_lds<<<gg, 256, 0, stream>>>(xb, wbr, b_row, qkv);
    attn_mfma<0><<<E_ * H_, 256, 0, stream>>>(qkv, attn, mask);
    add_ln<0, 1><<<M_ / 4, 256, 0, stream>>>(x, attn, g1, be1, out1b);

    // ---- column attention ----
    gemm_lds<<<gg, 256, 0, stream>>>(out1b, wbc, b_col, qkv);
    attn_mfma<1><<<L_ * H_, 256, 0, stream>>>(qkv, attn, mask);
    add_ln<1, 0><<<M_ / 4, 256, 0, stream>>>(out1b, attn, g2, be2, out);
}